// Round 4
// baseline (472.884 us; speedup 1.0000x reference)
//
#include <hip/hip_runtime.h>
#include <stdint.h>

#define N_TOK 32768
#define HID   1024
#define NE    8
#define NI    2048
#define CAP   4096

typedef short s16x8 __attribute__((ext_vector_type(8)));
typedef float f32x4 __attribute__((ext_vector_type(4)));

__device__ __forceinline__ unsigned short f2bf(float f) {
    unsigned int u = __builtin_bit_cast(unsigned int, f);
    u += 0x7fffu + ((u >> 16) & 1u);
    return (unsigned short)(u >> 16);
}

__device__ __forceinline__ void gload16(const void* g, void* l) {
    __builtin_amdgcn_global_load_lds(
        (const __attribute__((address_space(1))) unsigned int*)(uintptr_t)g,
        (__attribute__((address_space(3))) unsigned int*)(unsigned int)(uintptr_t)l,
        16, 0, 0);
}

#define WAIT_LGKM0 asm volatile("s_waitcnt lgkmcnt(0)" ::: "memory")
#define WAIT_VM6   asm volatile("s_waitcnt vmcnt(6)" ::: "memory")
#define WAIT_VM0   asm volatile("s_waitcnt vmcnt(0)" ::: "memory")
#define SFENCE     __builtin_amdgcn_sched_barrier(0)
#define BARR       __builtin_amdgcn_s_barrier()

// stage one 128-row x 64-col half-tile (2 x 1024B wave loads), pre-swizzled src
#define STAGE(Ms, rM, tile, h) do { \
    unsigned short* _d = Ms + (((tile) & 1) * 16384) + (h) * 8192 + wave * 1024; \
    gload16(rM[h][0] + (tile) * 64 + gsl8, _d); \
    gload16(rM[h][1] + (tile) * 64 + gsl8, _d + 512); } while (0)

// 16 MFMA: 4 mi x 4 nj at ni-base NB
#define MFMA_CL(AF, BF, NB) do { \
    __builtin_amdgcn_s_setprio(1); \
    _Pragma("unroll") \
    for (int mi = 0; mi < 4; ++mi) \
    _Pragma("unroll") \
    for (int nj = 0; nj < 4; ++nj) \
        acc[mi][(NB) + nj] = __builtin_amdgcn_mfma_f32_16x16x32_bf16( \
            AF[mi], BF[(NB) + nj], acc[mi][(NB) + nj], 0, 0, 0); \
    __builtin_amdgcn_s_setprio(0); \
} while (0)

#define RD_A(DST, PH) do { \
    _Pragma("unroll") \
    for (int mi = 0; mi < 4; ++mi) \
        DST[mi] = *(const s16x8*)(As + buf + abase + mi * 1024 + (PH)); \
} while (0)

#define RD_B(DST, PH, NB) do { \
    _Pragma("unroll") \
    for (int nj = 0; nj < 4; ++nj) \
        DST[(NB) + nj] = *(const s16x8*)(Bs + buf + bbase + ((NB) + nj) * 1024 + (PH)); \
} while (0)

// ---------------- fp32 -> bf16 bulk convert ----------------
__global__ __launch_bounds__(256) void cvt_kernel(
    const float* __restrict__ src, unsigned short* __restrict__ dst, size_t n8)
{
    size_t i = (size_t)blockIdx.x * 256 + threadIdx.x;
    size_t stride = (size_t)gridDim.x * 256;
    for (; i < n8; i += stride) {
        float4 a0 = ((const float4*)src)[2 * i];
        float4 a1 = ((const float4*)src)[2 * i + 1];
        uint4 p;
        p.x = f2bf(a0.x) | ((unsigned)f2bf(a0.y) << 16);
        p.y = f2bf(a0.z) | ((unsigned)f2bf(a0.w) << 16);
        p.z = f2bf(a1.x) | ((unsigned)f2bf(a1.y) << 16);
        p.w = f2bf(a1.z) | ((unsigned)f2bf(a1.w) << 16);
        ((uint4*)dst)[i] = p;
    }
}

// ---------------- Router: fp32 dot, top-2, softmax; fused x->bf16 ----------------
__global__ __launch_bounds__(256) void router_kernel(
    const float* __restrict__ x, const float* __restrict__ emb,
    int2* __restrict__ r_e, float2* __restrict__ r_w,
    unsigned short* __restrict__ xb)
{
    int token = blockIdx.x * 4 + (threadIdx.x >> 6);
    int lane  = threadIdx.x & 63;
    const float4* xr = (const float4*)(x + (size_t)token * HID);
    const float4* er = (const float4*)emb;

    float a[NE];
#pragma unroll
    for (int e = 0; e < NE; ++e) a[e] = 0.f;
    uint2 pk[4];
#pragma unroll
    for (int j = 0; j < 4; ++j) {
        float4 v = xr[j * 64 + lane];
        pk[j].x = f2bf(v.x) | ((unsigned)f2bf(v.y) << 16);
        pk[j].y = f2bf(v.z) | ((unsigned)f2bf(v.w) << 16);
#pragma unroll
        for (int e = 0; e < NE; ++e) {
            float4 w = er[e * 256 + j * 64 + lane];
            a[e] += v.x * w.x + v.y * w.y + v.z * w.z + v.w * w.w;
        }
    }
    uint2* xbr = (uint2*)(xb + (size_t)token * HID);
#pragma unroll
    for (int j = 0; j < 4; ++j) xbr[j * 64 + lane] = pk[j];

#pragma unroll
    for (int e = 0; e < NE; ++e) {
        for (int off = 32; off; off >>= 1) a[e] += __shfl_xor(a[e], off);
    }
    if (lane == 0) {
        float v1 = -1e30f, v2 = -1e30f; int i1 = 0, i2 = 0;
#pragma unroll
        for (int e = 0; e < NE; ++e) {
            float v = a[e];
            if (v > v1) { v2 = v1; i2 = i1; v1 = v; i1 = e; }
            else if (v > v2) { v2 = v; i2 = e; }
        }
        float ex = __expf(v2 - v1);
        r_e[token] = make_int2(i1, i2);
        r_w[token] = make_float2(1.f / (1.f + ex), ex / (1.f + ex));
    }
}

// ---------------- Capacity: count / prefix / ordered assign ----------------
__global__ __launch_bounds__(1024) void count_kernel(
    const int2* __restrict__ r_e, int* __restrict__ bc)
{
    __shared__ int cnt[NE];
    if (threadIdx.x < NE) cnt[threadIdx.x] = 0;
    __syncthreads();
    int n = blockIdx.x * 1024 + threadIdx.x;
    int2 e = r_e[n];
    atomicAdd(&cnt[e.x], 1);
    atomicAdd(&cnt[e.y], 1);
    __syncthreads();
    if (threadIdx.x < NE) bc[blockIdx.x * NE + threadIdx.x] = cnt[threadIdx.x];
}

__global__ void prefix_kernel(const int* __restrict__ bc, int* __restrict__ bb)
{
    int e = threadIdx.x;
    if (e >= NE) return;
    int run = 0;
    for (int b = 0; b < N_TOK / 1024; ++b) {
        bb[b * NE + e] = run;
        run += bc[b * NE + e];
    }
}

__global__ __launch_bounds__(1024) void assign_kernel(
    const int2* __restrict__ r_e, const float2* __restrict__ r_w,
    const int* __restrict__ bb,
    int* __restrict__ tok_list, float* __restrict__ w_list)
{
    __shared__ int wavecnt[16][NE];
    __shared__ int waveoff[16][NE];
    int tid = threadIdx.x, lane = tid & 63, wv = tid >> 6;
    int n = blockIdx.x * 1024 + tid;
    int2 e = r_e[n];
    float2 w = r_w[n];
    unsigned long long below = (1ull << lane) - 1ull;
    int rank0 = 0, rank1 = 0;
#pragma unroll
    for (int ex = 0; ex < NE; ++ex) {
        unsigned long long m = __ballot(e.x == ex || e.y == ex);
        if (lane == 0) wavecnt[wv][ex] = __popcll(m);
        int r = __popcll(m & below);
        if (e.x == ex) rank0 = r;
        if (e.y == ex) rank1 = r;
    }
    __syncthreads();
    if (tid < NE) {
        int run = 0;
        for (int w2 = 0; w2 < 16; ++w2) { waveoff[w2][tid] = run; run += wavecnt[w2][tid]; }
    }
    __syncthreads();
    int s0 = bb[blockIdx.x * NE + e.x] + waveoff[wv][e.x] + rank0;
    int s1 = bb[blockIdx.x * NE + e.y] + waveoff[wv][e.y] + rank1;
    if (s0 < CAP) { tok_list[e.x * CAP + s0] = n; w_list[e.x * CAP + s0] = w.x; }
    if (s1 < CAP) { tok_list[e.y * CAP + s1] = n; w_list[e.y * CAP + s1] = w.y; }
}

// ---------------- GEMM1: 256x256, pipelined slots, 2 barriers/tile ----------------
__global__ __launch_bounds__(512, 2) void gemm1_k(
    const unsigned short* __restrict__ xb,
    const unsigned short* __restrict__ w1b,
    const int* __restrict__ tok_list,
    unsigned short* __restrict__ inter,
    int eb)
{
    constexpr int K = HID, T = K / 64;
    __shared__ __align__(16) unsigned short smem[65536];
    unsigned short* As = smem;
    unsigned short* Bs = smem + 32768;

    const int nblk = gridDim.x;
    const int lin  = blockIdx.x;
    const int wg   = (lin & 7) * (nblk >> 3) + (lin >> 3);
    const int tn = wg & 7;
    const int tm = (wg >> 3) & 15;
    const int ez = wg >> 7;
    const int e  = eb + ez;

    const int tid = threadIdx.x, lane = tid & 63, wave = tid >> 6;
    const int wr = wave >> 1, wc = wave & 1;         // 4x2 wave grid: 64 x 128 per wave
    const int gsl8 = ((lane & 7) ^ (lane >> 3)) * 8;
    const int abase = (wr >> 1) * 8192 + (((wr & 1) * 64 + (lane & 15))) * 64;
    const int bbase = wc * 8192 + (lane & 15) * 64;
    const int ph0 = ((lane >> 4) ^ (lane & 7)) * 8;
    const int ph1 = ((4 + (lane >> 4)) ^ (lane & 7)) * 8;
    const int rbase = wave * 16 + (lane >> 3);

    const int* tl = tok_list + e * CAP + tm * 256;
    const unsigned short* rA[2][2];
    const unsigned short* rB[2][2];
#pragma unroll
    for (int h = 0; h < 2; ++h)
#pragma unroll
        for (int j = 0; j < 2; ++j) {
            rA[h][j] = xb + (size_t)tl[h * 128 + rbase + j * 8] * K;
            rB[h][j] = w1b + ((size_t)e * NI + tn * 256 + h * 128 + rbase + j * 8) * K;
        }

    f32x4 acc[4][8];
#pragma unroll
    for (int i = 0; i < 4; ++i)
#pragma unroll
        for (int j = 0; j < 8; ++j) acc[i][j] = (f32x4)0.f;

    s16x8 afr0[4], afr1[4], bfr0[8], bfr1[8];

    // prologue: tile0 (A0,A1,B0,B1) + tile1 (A0,B0,B1)
    STAGE(As, rA, 0, 0); STAGE(As, rA, 0, 1);
    STAGE(Bs, rB, 0, 0); STAGE(Bs, rB, 0, 1);
    STAGE(As, rA, 1, 0);
    STAGE(Bs, rB, 1, 0); STAGE(Bs, rB, 1, 1);
    WAIT_VM6; SFENCE; BARR; SFENCE;

#pragma unroll 2
    for (int t = 0; t < T; ++t) {
        const int buf = (t & 1) * 16384;
        // slot0: stage A1(t+1); read kh0 frags; MFMA kh0 x ni0-3
        if (t + 1 < T) STAGE(As, rA, t + 1, 1);
        RD_A(afr0, ph0);
        RD_B(bfr0, ph0, 0);
        RD_B(bfr0, ph0, 4);
        MFMA_CL(afr0, bfr0, 0);
        // slot1: read kh1 A; MFMA kh0 x ni4-7
        RD_A(afr1, ph1);
        MFMA_CL(afr0, bfr0, 4);
        // slot2: read kh1 B; MFMA kh1 x ni0-3
        RD_B(bfr1, ph1, 0);
        RD_B(bfr1, ph1, 4);
        MFMA_CL(afr1, bfr1, 0);
        // slot3: drain reads; barrier; stage t+2; MFMA kh1 x ni4-7; counted vmcnt
        WAIT_LGKM0; SFENCE; BARR; SFENCE;
        if (t + 2 < T) { STAGE(As, rA, t + 2, 0); STAGE(Bs, rB, t + 2, 0); STAGE(Bs, rB, t + 2, 1); }
        MFMA_CL(afr1, bfr1, 4);
        if (t < T - 2) { WAIT_VM6; } else { WAIT_VM0; }
        SFENCE; BARR; SFENCE;
    }

    // epilogue: relu + swizzled LDS repack -> coalesced 16B stores
    __syncthreads();
#pragma unroll
    for (int mi = 0; mi < 4; ++mi)
#pragma unroll
        for (int ni = 0; ni < 8; ++ni)
#pragma unroll
            for (int r = 0; r < 4; ++r) {
                int row = wr * 64 + mi * 16 + (lane >> 4) * 4 + r;
                int c   = wc * 128 + ni * 16 + (lane & 15);
                float v = acc[mi][ni][r];
                v = v > 0.f ? v : 0.f;
                smem[row * 256 + (((c >> 3) ^ (row & 7)) << 3) + (c & 7)] = f2bf(v);
            }
    __syncthreads();
    unsigned short* Cp = inter + ((size_t)ez * CAP + tm * 256) * NI + tn * 256;
#pragma unroll
    for (int it = 0; it < 16; ++it) {
        int v = tid + it * 512;
        int row = v >> 5, s = v & 31;
        uint4 val = *(const uint4*)&smem[row * 256 + ((s ^ (row & 7)) << 3)];
        *(uint4*)&Cp[(size_t)row * NI + s * 8] = val;
    }
}

// ---------------- GEMM2: same pipeline; atomic fp32 combine epilogue ----------------
__global__ __launch_bounds__(512, 2) void gemm2_k(
    const unsigned short* __restrict__ inter,
    const unsigned short* __restrict__ w2b,
    const int* __restrict__ tok_list,
    const float* __restrict__ w_list,
    float* __restrict__ out,
    int eb)
{
    constexpr int K = NI, T = K / 64;
    __shared__ __align__(16) unsigned short smem[65536];
    unsigned short* As = smem;
    unsigned short* Bs = smem + 32768;

    const int nblk = gridDim.x;
    const int lin  = blockIdx.x;
    const int wg   = (lin & 7) * (nblk >> 3) + (lin >> 3);
    const int tn = wg & 3;
    const int tm = (wg >> 2) & 15;
    const int ez = wg >> 6;
    const int e  = eb + ez;

    const int tid = threadIdx.x, lane = tid & 63, wave = tid >> 6;
    const int wr = wave >> 1, wc = wave & 1;
    const int gsl8 = ((lane & 7) ^ (lane >> 3)) * 8;
    const int abase = (wr >> 1) * 8192 + (((wr & 1) * 64 + (lane & 15))) * 64;
    const int bbase = wc * 8192 + (lane & 15) * 64;
    const int ph0 = ((lane >> 4) ^ (lane & 7)) * 8;
    const int ph1 = ((4 + (lane >> 4)) ^ (lane & 7)) * 8;
    const int rbase = wave * 16 + (lane >> 3);

    const unsigned short* rA[2][2];
    const unsigned short* rB[2][2];
#pragma unroll
    for (int h = 0; h < 2; ++h)
#pragma unroll
        for (int j = 0; j < 2; ++j) {
            rA[h][j] = inter + ((size_t)ez * CAP + tm * 256 + h * 128 + rbase + j * 8) * (size_t)K;
            rB[h][j] = w2b + ((size_t)e * HID + tn * 256 + h * 128 + rbase + j * 8) * (size_t)K;
        }

    f32x4 acc[4][8];
#pragma unroll
    for (int i = 0; i < 4; ++i)
#pragma unroll
        for (int j = 0; j < 8; ++j) acc[i][j] = (f32x4)0.f;

    s16x8 afr0[4], afr1[4], bfr0[8], bfr1[8];

    STAGE(As, rA, 0, 0); STAGE(As, rA, 0, 1);
    STAGE(Bs, rB, 0, 0); STAGE(Bs, rB, 0, 1);
    STAGE(As, rA, 1, 0);
    STAGE(Bs, rB, 1, 0); STAGE(Bs, rB, 1, 1);
    WAIT_VM6; SFENCE; BARR; SFENCE;

#pragma unroll 2
    for (int t = 0; t < T; ++t) {
        const int buf = (t & 1) * 16384;
        if (t + 1 < T) STAGE(As, rA, t + 1, 1);
        RD_A(afr0, ph0);
        RD_B(bfr0, ph0, 0);
        RD_B(bfr0, ph0, 4);
        MFMA_CL(afr0, bfr0, 0);
        RD_A(afr1, ph1);
        MFMA_CL(afr0, bfr0, 4);
        RD_B(bfr1, ph1, 0);
        RD_B(bfr1, ph1, 4);
        MFMA_CL(afr1, bfr1, 0);
        WAIT_LGKM0; SFENCE; BARR; SFENCE;
        if (t + 2 < T) { STAGE(As, rA, t + 2, 0); STAGE(Bs, rB, t + 2, 0); STAGE(Bs, rB, t + 2, 1); }
        MFMA_CL(afr1, bfr1, 4);
        if (t < T - 2) { WAIT_VM6; } else { WAIT_VM0; }
        SFENCE; BARR; SFENCE;
    }

    const int* tl   = tok_list + e * CAP + tm * 256;
    const float* wl = w_list  + e * CAP + tm * 256;
#pragma unroll
    for (int mi = 0; mi < 4; ++mi)
#pragma unroll
        for (int r = 0; r < 4; ++r) {
            int rrow = wr * 64 + mi * 16 + (lane >> 4) * 4 + r;
            int tok  = tl[rrow];
            float w  = wl[rrow];
            float* orow = out + (size_t)tok * HID + tn * 256 + wc * 128;
#pragma unroll
            for (int ni = 0; ni < 8; ++ni)
                atomicAdd(&orow[ni * 16 + (lane & 15)], acc[mi][ni][r] * w);
        }
}

extern "C" void kernel_launch(void* const* d_in, const int* in_sizes, int n_in,
                              void* d_out, int out_size, void* d_ws, size_t ws_size,
                              hipStream_t stream)
{
    const float* x   = (const float*)d_in[0];
    const float* emb = (const float*)d_in[1];
    const float* W1  = (const float*)d_in[2];
    const float* W2  = (const float*)d_in[3];
    float* out = (float*)d_out;

    size_t off = 0;
    auto alloc = [&](size_t bytes) -> void* {
        void* p = (char*)d_ws + off;
        off += (bytes + 255) & ~(size_t)255;
        return p;
    };
    const size_t sz_w  = (size_t)NE * NI * HID * 2;
    const size_t sz_xb = (size_t)N_TOK * HID * 2;

    int*   tok_list = (int*)alloc((size_t)NE * CAP * 4);
    float* w_list   = (float*)alloc((size_t)NE * CAP * 4);
    unsigned short* w1b = (unsigned short*)alloc(sz_w);
    unsigned short* w2b = (unsigned short*)alloc(sz_w);
    unsigned short* xb  = (unsigned short*)alloc(sz_xb);

    unsigned short* inter = (unsigned short*)((char*)d_ws + off);
    size_t avail = ws_size > off ? ws_size - off : 0;
    const size_t per_e = (size_t)CAP * NI * 2;
    int G = (avail >= 8 * per_e) ? 8 : (avail >= 4 * per_e) ? 4
          : (avail >= 2 * per_e) ? 2 : 1;

    int2*   r_e = (int2*)inter;
    float2* r_w = (float2*)((char*)inter + (size_t)N_TOK * 8);
    int*    bc  = (int*)((char*)inter + (size_t)N_TOK * 16);
    int*    bb  = bc + (N_TOK / 1024) * NE;

    hipMemsetAsync(d_out, 0, (size_t)N_TOK * HID * 4, stream);
    hipMemsetAsync(tok_list, 0, (size_t)NE * CAP * 4, stream);
    hipMemsetAsync(w_list, 0, (size_t)NE * CAP * 4, stream);

    cvt_kernel<<<2048, 256, 0, stream>>>(W1, w1b, (size_t)NE * NI * HID / 8);
    cvt_kernel<<<2048, 256, 0, stream>>>(W2, w2b, (size_t)NE * HID * NI / 8);
    router_kernel<<<N_TOK / 4, 256, 0, stream>>>(x, emb, r_e, r_w, xb);
    count_kernel<<<N_TOK / 1024, 1024, 0, stream>>>(r_e, bc);
    prefix_kernel<<<1, 64, 0, stream>>>(bc, bb);
    assign_kernel<<<N_TOK / 1024, 1024, 0, stream>>>(r_e, r_w, bb, tok_list, w_list);

    for (int eb = 0; eb < NE; eb += G) {
        gemm1_k<<<dim3(8 * 16 * G), 512, 0, stream>>>(xb, w1b, tok_list, inter, eb);
        gemm2_k<<<dim3(4 * 16 * G), 512, 0, stream>>>(inter, w2b, tok_list, w_list, out, eb);
    }
}